// Round 10
// baseline (387.091 us; speedup 1.0000x reference)
//
#include <hip/hip_runtime.h>

// GenericVNet: out = L(x) @ gradE(x) + V(x) (V(x)^T gradS(x))
// D=4, H=32, R=4, B=1M, fp32. VALU compute-bound (~10.5 GFLOP, 32 MB HBM).
//
// R2: h1+h2+g1 live -> AGPR spill shuttle (VGPR=68, occ 33%), 329us.
// R3: launch_bounds(256,5) cap=102 -> scratch spill (WRITE 51.6MB), 297us.
// R7: launch_bounds(256,3) + packed fp32 -> STILL spills (VGPR=64, WRITE
//     33.5MB = out 16.4 + ~17 spill, occ 42%), 262us. Lesson: launch_bounds
//     sets only the register CAP; the allocator still TARGETS max occupancy
//     and spills to hold VGPR=64.
// R8-R10: pin the target: __attribute__((amdgpu_waves_per_eu(4,4))) ->
//     exactly 4 waves/EU, firm 128-reg budget the allocator will use. Live
//     set ~90 regs < 128 -> no spill, 50% occupancy. Otherwise identical to
//     R7 for a clean A/B. (R8/R9 never ran: infra failures. Resubmit.)

namespace {

constexpr int D = 4;
constexpr int H = 32;
constexpr int H2 = H / 2;
constexpr int R = 4;

typedef float v2f __attribute__((ext_vector_type(2)));

__device__ __forceinline__ v2f fma2(v2f a, v2f b, v2f c) {
  return __builtin_elementwise_fma(a, b, c);
}

__device__ __forceinline__ float fast_rcp(float v) {
#if defined(__has_builtin)
#if __has_builtin(__builtin_amdgcn_rcpf)
  return __builtin_amdgcn_rcpf(v);
#else
  return 1.0f / v;
#endif
#else
  return 1.0f / v;
#endif
}

__device__ __forceinline__ float fast_exp2(float v) {
#if defined(__has_builtin)
#if __has_builtin(__builtin_amdgcn_exp2f)
  return __builtin_amdgcn_exp2f(v);
#else
  return exp2f(v);
#endif
#else
  return exp2f(v);
#endif
}

__device__ __forceinline__ float fast_tanh(float v) {
  // tanh(v) = 1 - 2/(exp(2v)+1); exp(2v) = exp2(v * 2*log2(e)).
  float e = fast_exp2(v * 2.885390081777926f);
  return 1.0f - 2.0f * fast_rcp(e + 1.0f);
}

__device__ __forceinline__ v2f tanh2(v2f v) {
  v2f r;
  r.x = fast_tanh(v.x);
  r.y = fast_tanh(v.y);
  return r;
}

__global__ __launch_bounds__(256)
__attribute__((amdgpu_waves_per_eu(4, 4)))
void vnet_kernel(
    const float* __restrict__ x,
    const float* __restrict__ Ew1, const float* __restrict__ Eb1,
    const float* __restrict__ Ew2, const float* __restrict__ Eb2,
    const float* __restrict__ Ew3, const float* __restrict__ Eb3,
    const float* __restrict__ Sw1, const float* __restrict__ Sb1,
    const float* __restrict__ Sw2, const float* __restrict__ Sb2,
    const float* __restrict__ Sw3, const float* __restrict__ Sb3,
    const float* __restrict__ Lw, const float* __restrict__ Lb,
    const float* __restrict__ Mw, const float* __restrict__ Mb,
    float* __restrict__ out, int n) {
  int tid = blockIdx.x * blockDim.x + threadIdx.x;
  if (tid >= n) return;

  float4 xv = reinterpret_cast<const float4*>(x)[tid];
  float xr[D] = {xv.x, xv.y, xv.z, xv.w};

  float gE[D], gS[D];
  const v2f one2 = {1.0f, 1.0f};

  // One code copy for both MLPs; weight pointers are wave-uniform selects so
  // all weight reads stay scalar (s_load pairs feeding VOP3P as SGPR64).
#pragma unroll 1
  for (int net = 0; net < 2; ++net) {
    const v2f* __restrict__ w1p =
        reinterpret_cast<const v2f*>(net ? Sw1 : Ew1);
    const v2f* __restrict__ b1p =
        reinterpret_cast<const v2f*>(net ? Sb1 : Eb1);
    const v2f* __restrict__ w2p =
        reinterpret_cast<const v2f*>(net ? Sw2 : Ew2);
    const v2f* __restrict__ b2p =
        reinterpret_cast<const v2f*>(net ? Sb2 : Eb2);
    const v2f* __restrict__ w3p =
        reinterpret_cast<const v2f*>(net ? Sw3 : Ew3);

    // ---- layer 1: h1 = tanh(x @ w1 + b1), packed over j ----
    v2f h1[H2];
#pragma unroll
    for (int j2 = 0; j2 < H2; ++j2) h1[j2] = b1p[j2];
#pragma unroll
    for (int i = 0; i < D; ++i) {
      v2f xi = {xr[i], xr[i]};
#pragma unroll
      for (int j2 = 0; j2 < H2; ++j2)
        h1[j2] = fma2(xi, w1p[i * H2 + j2], h1[j2]);
    }
#pragma unroll
    for (int j2 = 0; j2 < H2; ++j2) h1[j2] = tanh2(h1[j2]);

    // ---- layer 2 fwd (packed over j), fused with top of backward ----
    // g2 holds pre2 -> d_pre2 = w3 * (1 - tanh(pre2)^2) in place.
    v2f g2[H2];
#pragma unroll
    for (int j2 = 0; j2 < H2; ++j2) g2[j2] = b2p[j2];
#pragma unroll
    for (int k = 0; k < H; ++k) {
      float hk = (k & 1) ? h1[k >> 1].y : h1[k >> 1].x;
      v2f hb = {hk, hk};
#pragma unroll
      for (int j2 = 0; j2 < H2; ++j2)
        g2[j2] = fma2(hb, w2p[k * H2 + j2], g2[j2]);
    }
#pragma unroll
    for (int j2 = 0; j2 < H2; ++j2) {
      v2f t = tanh2(g2[j2]);
      g2[j2] = w3p[j2] * (one2 - t * t);
    }

    // ---- backward: d_pre1 pairs fused straight into grad accumulation ----
    // Two adjacent k per step share the g2 operand; grad packed over k so
    // w1 pairs (w1[i*H+2k2], w1[i*H+2k2+1]) are contiguous.
    v2f acc0 = {0.0f, 0.0f}, acc1 = {0.0f, 0.0f};
    v2f acc2 = {0.0f, 0.0f}, acc3 = {0.0f, 0.0f};
#pragma unroll
    for (int k2 = 0; k2 < H2; ++k2) {
      v2f s0 = {0.0f, 0.0f}, s1 = {0.0f, 0.0f};
#pragma unroll
      for (int j2 = 0; j2 < H2; ++j2) {
        v2f g = g2[j2];
        s0 = fma2(w2p[(2 * k2) * H2 + j2], g, s0);
        s1 = fma2(w2p[(2 * k2 + 1) * H2 + j2], g, s1);
      }
      float ha = h1[k2].x, hb = h1[k2].y;
      float sa = (s0.x + s0.y) * (1.0f - ha * ha);
      float sb = (s1.x + s1.y) * (1.0f - hb * hb);
      v2f g1p = {sa, sb};
      acc0 = fma2(w1p[0 * H2 + k2], g1p, acc0);
      acc1 = fma2(w1p[1 * H2 + k2], g1p, acc1);
      acc2 = fma2(w1p[2 * H2 + k2], g1p, acc2);
      acc3 = fma2(w1p[3 * H2 + k2], g1p, acc3);
    }

    if (net == 0) {
      gE[0] = acc0.x + acc0.y; gE[1] = acc1.x + acc1.y;
      gE[2] = acc2.x + acc2.y; gE[3] = acc3.x + acc3.y;
    } else {
      gS[0] = acc0.x + acc0.y; gS[1] = acc1.x + acc1.y;
      gS[2] = acc2.x + acc2.y; gS[3] = acc3.x + acc3.y;
    }
  }

  // ---- L head: Bm = x @ Lw + Lb (16 outputs), packed over e ----
  v2f Bmp[D * D / 2];
  {
    const v2f* __restrict__ Lbp = reinterpret_cast<const v2f*>(Lb);
    const v2f* __restrict__ Lwp = reinterpret_cast<const v2f*>(Lw);
#pragma unroll
    for (int e2 = 0; e2 < D * D / 2; ++e2) Bmp[e2] = Lbp[e2];
#pragma unroll
    for (int i = 0; i < D; ++i) {
      v2f xi = {xr[i], xr[i]};
#pragma unroll
      for (int e2 = 0; e2 < D * D / 2; ++e2)
        Bmp[e2] = fma2(xi, Lwp[i * (D * D / 2) + e2], Bmp[e2]);
    }
  }
  const float* Bm = reinterpret_cast<const float*>(Bmp);

  // ---- M head: V = x @ Mw + Mb (16 outputs), packed over e ----
  v2f Vp[D * R / 2];
  {
    const v2f* __restrict__ Mbp = reinterpret_cast<const v2f*>(Mb);
    const v2f* __restrict__ Mwp = reinterpret_cast<const v2f*>(Mw);
#pragma unroll
    for (int e2 = 0; e2 < D * R / 2; ++e2) Vp[e2] = Mbp[e2];
#pragma unroll
    for (int i = 0; i < D; ++i) {
      v2f xi = {xr[i], xr[i]};
#pragma unroll
      for (int e2 = 0; e2 < D * R / 2; ++e2)
        Vp[e2] = fma2(xi, Mwp[i * (D * R / 2) + e2], Vp[e2]);
    }
  }
  const float* V = reinterpret_cast<const float*>(Vp);

  // u[r] = sum_i V[i][r] * gS[i]
  float u[R];
#pragma unroll
  for (int r = 0; r < R; ++r) {
    float a = 0.0f;
#pragma unroll
    for (int i = 0; i < D; ++i) a = fmaf(V[i * R + r], gS[i], a);
    u[r] = a;
  }

  // out[i] = sum_j (Bm[i][j]-Bm[j][i]) * gE[j] + sum_r V[i][r] * u[r]
  float o[D];
#pragma unroll
  for (int i = 0; i < D; ++i) {
    float a = 0.0f;
#pragma unroll
    for (int j = 0; j < D; ++j)
      a = fmaf(Bm[i * D + j] - Bm[j * D + i], gE[j], a);
#pragma unroll
    for (int r = 0; r < R; ++r) a = fmaf(V[i * R + r], u[r], a);
    o[i] = a;
  }

  reinterpret_cast<float4*>(out)[tid] = make_float4(o[0], o[1], o[2], o[3]);
}

}  // namespace

extern "C" void kernel_launch(void* const* d_in, const int* in_sizes, int n_in,
                              void* d_out, int out_size, void* d_ws, size_t ws_size,
                              hipStream_t stream) {
  const float* x   = (const float*)d_in[0];
  const float* Ew1 = (const float*)d_in[1];
  const float* Eb1 = (const float*)d_in[2];
  const float* Ew2 = (const float*)d_in[3];
  const float* Eb2 = (const float*)d_in[4];
  const float* Ew3 = (const float*)d_in[5];
  const float* Eb3 = (const float*)d_in[6];
  const float* Sw1 = (const float*)d_in[7];
  const float* Sb1 = (const float*)d_in[8];
  const float* Sw2 = (const float*)d_in[9];
  const float* Sb2 = (const float*)d_in[10];
  const float* Sw3 = (const float*)d_in[11];
  const float* Sb3 = (const float*)d_in[12];
  const float* Lw  = (const float*)d_in[13];
  const float* Lb  = (const float*)d_in[14];
  const float* Mw  = (const float*)d_in[15];
  const float* Mb  = (const float*)d_in[16];
  float* out = (float*)d_out;

  int n = in_sizes[0] / D;  // number of samples
  const int block = 256;
  int grid = (n + block - 1) / block;
  vnet_kernel<<<grid, block, 0, stream>>>(x, Ew1, Eb1, Ew2, Eb2, Ew3, Eb3,
                                          Sw1, Sb1, Sw2, Sb2, Sw3, Sb3,
                                          Lw, Lb, Mw, Mb, out, n);
}

// Round 11
// 229.320 us; speedup vs baseline: 1.6880x; 1.6880x over previous
//
#include <hip/hip_runtime.h>

// GenericVNet: out = L(x) @ gradE(x) + V(x) (V(x)^T gradS(x))
// D=4, H=32, R=4, B=1M, fp32. VALU compute-bound (~10.5 GFLOP, 32 MB HBM).
//
// Register-pressure history:
//   R2  (no attrs):            VGPR=64-ish, AGPR shuttle, occ 33%, 329us
//   R3  (launch_bounds(256,5)): VGPR=48, scratch spill 35MB, 297us
//   R7  (lb(256,3) + pk-fma):   VGPR=64, spill 17MB, occ 42%, 262us
//   R10 (waves_per_eu(4,4)):    VGPR=64, spill 40MB!, occ 44%, 361us
// LESSON: the allocator always targets 64 arch VGPRs (8 waves/SIMD max) and
// spills the overflow; attributes change the budget, not the target.
// R11: restructure so peak live fits 64 regs: NEVER materialize h1[32].
// Recompute h1 in chunks of 8 (4 FMA + tanh each, from always-live x) in
// both the L2-forward accumulation and the backward pass. Peak live ~52
// floats (g2[32]+chunk[8]+acc+x) -> no spill AT the allocator's natural
// target. ~+12% recompute ops, -100% spill tax. No occupancy attributes.

namespace {

constexpr int D = 4;
constexpr int H = 32;
constexpr int H2 = H / 2;
constexpr int R = 4;

typedef float v2f __attribute__((ext_vector_type(2)));

__device__ __forceinline__ v2f fma2(v2f a, v2f b, v2f c) {
  return __builtin_elementwise_fma(a, b, c);
}

__device__ __forceinline__ float fast_rcp(float v) {
#if defined(__has_builtin)
#if __has_builtin(__builtin_amdgcn_rcpf)
  return __builtin_amdgcn_rcpf(v);
#else
  return 1.0f / v;
#endif
#else
  return 1.0f / v;
#endif
}

__device__ __forceinline__ float fast_exp2(float v) {
#if defined(__has_builtin)
#if __has_builtin(__builtin_amdgcn_exp2f)
  return __builtin_amdgcn_exp2f(v);
#else
  return exp2f(v);
#endif
#else
  return exp2f(v);
#endif
}

__device__ __forceinline__ float fast_tanh(float v) {
  // tanh(v) = 1 - 2/(exp(2v)+1); exp(2v) = exp2(v * 2*log2(e)).
  float e = fast_exp2(v * 2.885390081777926f);
  return 1.0f - 2.0f * fast_rcp(e + 1.0f);
}

__device__ __forceinline__ v2f tanh2(v2f v) {
  v2f r;
  r.x = fast_tanh(v.x);
  r.y = fast_tanh(v.y);
  return r;
}

__global__ __launch_bounds__(256) void vnet_kernel(
    const float* __restrict__ x,
    const float* __restrict__ Ew1, const float* __restrict__ Eb1,
    const float* __restrict__ Ew2, const float* __restrict__ Eb2,
    const float* __restrict__ Ew3, const float* __restrict__ Eb3,
    const float* __restrict__ Sw1, const float* __restrict__ Sb1,
    const float* __restrict__ Sw2, const float* __restrict__ Sb2,
    const float* __restrict__ Sw3, const float* __restrict__ Sb3,
    const float* __restrict__ Lw, const float* __restrict__ Lb,
    const float* __restrict__ Mw, const float* __restrict__ Mb,
    float* __restrict__ out, int n) {
  int tid = blockIdx.x * blockDim.x + threadIdx.x;
  if (tid >= n) return;

  float4 xv = reinterpret_cast<const float4*>(x)[tid];
  float xr[D] = {xv.x, xv.y, xv.z, xv.w};

  float gE[D], gS[D];
  const v2f one2 = {1.0f, 1.0f};

  // One code copy for both MLPs; weight pointers are wave-uniform selects so
  // all weight reads stay scalar (s_load, SGPR operands of v_fma/v_pk_fma).
#pragma unroll 1
  for (int net = 0; net < 2; ++net) {
    const float* __restrict__ w1 = net ? Sw1 : Ew1;
    const v2f* __restrict__ w1p = reinterpret_cast<const v2f*>(w1);
    const v2f* __restrict__ b1p =
        reinterpret_cast<const v2f*>(net ? Sb1 : Eb1);
    const v2f* __restrict__ w2p =
        reinterpret_cast<const v2f*>(net ? Sw2 : Ew2);
    const v2f* __restrict__ b2p =
        reinterpret_cast<const v2f*>(net ? Sb2 : Eb2);
    const v2f* __restrict__ w3p =
        reinterpret_cast<const v2f*>(net ? Sw3 : Ew3);

    // ---- Phase A: g2 = x@W1 -> tanh -> @W2 accumulation, h1 recomputed in
    //      chunks of 8 (hp[4] v2f), never all 32 live at once ----
    v2f g2[H2];
#pragma unroll
    for (int j2 = 0; j2 < H2; ++j2) g2[j2] = b2p[j2];

#pragma unroll 1
    for (int kc = 0; kc < 4; ++kc) {
      // recompute h1[kc*8 .. kc*8+7]
      v2f hp[4];
#pragma unroll
      for (int t2 = 0; t2 < 4; ++t2) hp[t2] = b1p[kc * 4 + t2];
#pragma unroll
      for (int i = 0; i < D; ++i) {
        v2f xi = {xr[i], xr[i]};
#pragma unroll
        for (int t2 = 0; t2 < 4; ++t2)
          hp[t2] = fma2(xi, w1p[i * H2 + kc * 4 + t2], hp[t2]);
      }
#pragma unroll
      for (int t2 = 0; t2 < 4; ++t2) hp[t2] = tanh2(hp[t2]);

      // g2 += h1[k] * w2[k,:] for the chunk
#pragma unroll
      for (int t = 0; t < 8; ++t) {
        float hk = (t & 1) ? hp[t >> 1].y : hp[t >> 1].x;
        v2f hb = {hk, hk};
        int k = kc * 8 + t;
#pragma unroll
        for (int j2 = 0; j2 < H2; ++j2)
          g2[j2] = fma2(hb, w2p[k * H2 + j2], g2[j2]);
      }
    }

    // g2: pre2 -> d_pre2 = w3 * (1 - tanh(pre2)^2), in place
#pragma unroll
    for (int j2 = 0; j2 < H2; ++j2) {
      v2f t = tanh2(g2[j2]);
      g2[j2] = w3p[j2] * (one2 - t * t);
    }

    // ---- Phase B: grad[i] = sum_k w1[i,k]*(1-h1k^2)*(w2[k,:].g2),
    //      h1 recomputed per chunk again ----
    float acc[D] = {0.0f, 0.0f, 0.0f, 0.0f};
#pragma unroll 1
    for (int kc = 0; kc < 4; ++kc) {
      v2f hp[4];
#pragma unroll
      for (int t2 = 0; t2 < 4; ++t2) hp[t2] = b1p[kc * 4 + t2];
#pragma unroll
      for (int i = 0; i < D; ++i) {
        v2f xi = {xr[i], xr[i]};
#pragma unroll
        for (int t2 = 0; t2 < 4; ++t2)
          hp[t2] = fma2(xi, w1p[i * H2 + kc * 4 + t2], hp[t2]);
      }
#pragma unroll
      for (int t2 = 0; t2 < 4; ++t2) hp[t2] = tanh2(hp[t2]);

#pragma unroll
      for (int t = 0; t < 8; ++t) {
        int k = kc * 8 + t;
        float hk = (t & 1) ? hp[t >> 1].y : hp[t >> 1].x;
        v2f s2 = {0.0f, 0.0f};
#pragma unroll
        for (int j2 = 0; j2 < H2; ++j2)
          s2 = fma2(w2p[k * H2 + j2], g2[j2], s2);
        float s = (s2.x + s2.y) * (1.0f - hk * hk);
#pragma unroll
        for (int i = 0; i < D; ++i) acc[i] = fmaf(w1[i * H + k], s, acc[i]);
      }
    }

    if (net == 0) {
#pragma unroll
      for (int i = 0; i < D; ++i) gE[i] = acc[i];
    } else {
#pragma unroll
      for (int i = 0; i < D; ++i) gS[i] = acc[i];
    }
  }

  // ---- L head: Bm = x @ Lw + Lb (16 outputs), packed over e ----
  v2f Bmp[D * D / 2];
  {
    const v2f* __restrict__ Lbp = reinterpret_cast<const v2f*>(Lb);
    const v2f* __restrict__ Lwp = reinterpret_cast<const v2f*>(Lw);
#pragma unroll
    for (int e2 = 0; e2 < D * D / 2; ++e2) Bmp[e2] = Lbp[e2];
#pragma unroll
    for (int i = 0; i < D; ++i) {
      v2f xi = {xr[i], xr[i]};
#pragma unroll
      for (int e2 = 0; e2 < D * D / 2; ++e2)
        Bmp[e2] = fma2(xi, Lwp[i * (D * D / 2) + e2], Bmp[e2]);
    }
  }
  const float* Bm = reinterpret_cast<const float*>(Bmp);

  // ---- M head: V = x @ Mw + Mb (16 outputs), packed over e ----
  v2f Vp[D * R / 2];
  {
    const v2f* __restrict__ Mbp = reinterpret_cast<const v2f*>(Mb);
    const v2f* __restrict__ Mwp = reinterpret_cast<const v2f*>(Mw);
#pragma unroll
    for (int e2 = 0; e2 < D * R / 2; ++e2) Vp[e2] = Mbp[e2];
#pragma unroll
    for (int i = 0; i < D; ++i) {
      v2f xi = {xr[i], xr[i]};
#pragma unroll
      for (int e2 = 0; e2 < D * R / 2; ++e2)
        Vp[e2] = fma2(xi, Mwp[i * (D * R / 2) + e2], Vp[e2]);
    }
  }
  const float* V = reinterpret_cast<const float*>(Vp);

  // u[r] = sum_i V[i][r] * gS[i]
  float u[R];
#pragma unroll
  for (int r = 0; r < R; ++r) {
    float a = 0.0f;
#pragma unroll
    for (int i = 0; i < D; ++i) a = fmaf(V[i * R + r], gS[i], a);
    u[r] = a;
  }

  // out[i] = sum_j (Bm[i][j]-Bm[j][i]) * gE[j] + sum_r V[i][r] * u[r]
  float o[D];
#pragma unroll
  for (int i = 0; i < D; ++i) {
    float a = 0.0f;
#pragma unroll
    for (int j = 0; j < D; ++j)
      a = fmaf(Bm[i * D + j] - Bm[j * D + i], gE[j], a);
#pragma unroll
    for (int r = 0; r < R; ++r) a = fmaf(V[i * R + r], u[r], a);
    o[i] = a;
  }

  reinterpret_cast<float4*>(out)[tid] = make_float4(o[0], o[1], o[2], o[3]);
}

}  // namespace

extern "C" void kernel_launch(void* const* d_in, const int* in_sizes, int n_in,
                              void* d_out, int out_size, void* d_ws, size_t ws_size,
                              hipStream_t stream) {
  const float* x   = (const float*)d_in[0];
  const float* Ew1 = (const float*)d_in[1];
  const float* Eb1 = (const float*)d_in[2];
  const float* Ew2 = (const float*)d_in[3];
  const float* Eb2 = (const float*)d_in[4];
  const float* Ew3 = (const float*)d_in[5];
  const float* Eb3 = (const float*)d_in[6];
  const float* Sw1 = (const float*)d_in[7];
  const float* Sb1 = (const float*)d_in[8];
  const float* Sw2 = (const float*)d_in[9];
  const float* Sb2 = (const float*)d_in[10];
  const float* Sw3 = (const float*)d_in[11];
  const float* Sb3 = (const float*)d_in[12];
  const float* Lw  = (const float*)d_in[13];
  const float* Lb  = (const float*)d_in[14];
  const float* Mw  = (const float*)d_in[15];
  const float* Mb  = (const float*)d_in[16];
  float* out = (float*)d_out;

  int n = in_sizes[0] / D;  // number of samples
  const int block = 256;
  int grid = (n + block - 1) / block;
  vnet_kernel<<<grid, block, 0, stream>>>(x, Ew1, Eb1, Ew2, Eb2, Ew3, Eb3,
                                          Sw1, Sb1, Sw2, Sb2, Sw3, Sb3,
                                          Lw, Lb, Mw, Mb, out, n);
}